// Round 2
// baseline (27830.096 us; speedup 1.0000x reference)
//
#include <hip/hip_runtime.h>
#include <stdint.h>

typedef unsigned short u16;
typedef unsigned int u32;
typedef __attribute__((ext_vector_type(8))) short short8;
typedef __attribute__((ext_vector_type(4))) float f32x4;

#define T_SEQ 512
#define NB 32
#define EMBD 1024
#define HID 512
#define G4 2048
#define NROWS (T_SEQ * NB)  // 16384
#define XPW 4096
#define NWPD 8   // workgroups per direction (sync participants)
#define UPW 64   // hidden units per WG

static __device__ __forceinline__ u16 f2bf(float x) {
  unsigned u = __float_as_uint(x);
  u += 0x7fffu + ((u >> 16) & 1u);
  return (u16)(u >> 16);
}
static __device__ __forceinline__ float bf2f(u16 b) {
  return __uint_as_float(((unsigned)b) << 16);
}
static __device__ __forceinline__ f32x4 mfma16(short8 a, short8 b, f32x4 c) {
  return __builtin_amdgcn_mfma_f32_16x16x32_bf16(a, b, c, 0, 0, 0);
}

// ---------------- weight prep: bf16 convert, Whh split hi/lo, bias merge ----
__global__ void k_prep(const float* __restrict__ Wih, const float* __restrict__ Whh,
                       const float* __restrict__ bih, const float* __restrict__ bhh,
                       u16* __restrict__ wih_b, u16* __restrict__ whh_hi,
                       u16* __restrict__ whh_lo, float* __restrict__ bcat) {
  size_t stride = (size_t)gridDim.x * blockDim.x;
  size_t i0 = (size_t)blockIdx.x * blockDim.x + threadIdx.x;
  const size_t n_ih = (size_t)2 * 2 * G4 * EMBD;  // [l][d][4H][E]
  for (size_t i = i0; i < n_ih; i += stride) wih_b[i] = f2bf(Wih[i]);
  const size_t n_hh = (size_t)2 * 2 * G4 * HID;   // [l][d][4H][H]
  for (size_t i = i0; i < n_hh; i += stride) {
    float w = Whh[i];
    u16 hi = f2bf(w);
    whh_hi[i] = hi;
    whh_lo[i] = f2bf(w - bf2f(hi));
  }
  for (size_t i = i0; i < 2 * 4096; i += stride) {
    size_t l = i >> 12, col = i & 4095;  // col = d*2048+g*512+u
    bcat[i] = bih[l * 4096 + col] + bhh[l * 4096 + col];
  }
}

// ---------------- embedding gather -> bf16 X [T*B, 1024] --------------------
__global__ void k_gather(const int* __restrict__ inp, const float* __restrict__ emb,
                         u16* __restrict__ X) {
  int row = blockIdx.x;  // t*32 + b
  int t = row >> 5, b = row & 31;
  int tok = inp[b * T_SEQ + t];
  const float* src = emb + (size_t)tok * EMBD + threadIdx.x * 4;
  float4 v = *reinterpret_cast<const float4*>(src);
  ushort4 o;
  o.x = f2bf(v.x); o.y = f2bf(v.y); o.z = f2bf(v.z); o.w = f2bf(v.w);
  *reinterpret_cast<ushort4*>(X + (size_t)row * EMBD + threadIdx.x * 4) = o;
}

// ---------------- xp GEMM: C[M,4096] = A[M,1024] @ B[4096,1024]^T + bias ----
#define GBM 128
#define GBN 128
#define GBK 64
__global__ __launch_bounds__(256) void k_gemm(const u16* __restrict__ A,
                                              const u16* __restrict__ B,
                                              const float* __restrict__ bias,
                                              u16* __restrict__ C) {
  __shared__ u16 As[GBM][GBK];
  __shared__ u16 Bs[GBN][GBK];
  const int Kdim = 1024, Ndim = 4096;
  int bm = blockIdx.x, bn = blockIdx.y;
  int tid = threadIdx.x;
  int lane = tid & 63, wave = tid >> 6;
  int wm = wave >> 1, wn = wave & 1;
  int l15 = lane & 15, klo = (lane >> 4) * 8;
  f32x4 acc[4][4] = {};
  for (int k0 = 0; k0 < Kdim; k0 += GBK) {
#pragma unroll
    for (int s = 0; s < 4; s++) {
      int seg = tid + s * 256;
      int r = seg >> 3, cs = (seg & 7) * 8;
      *reinterpret_cast<short8*>(&As[r][cs]) =
          *reinterpret_cast<const short8*>(A + (size_t)(bm * GBM + r) * Kdim + k0 + cs);
      *reinterpret_cast<short8*>(&Bs[r][cs]) =
          *reinterpret_cast<const short8*>(B + (size_t)(bn * GBN + r) * Kdim + k0 + cs);
    }
    __syncthreads();
#pragma unroll
    for (int kk = 0; kk < GBK; kk += 32) {
      short8 af[4], bfb[4];
#pragma unroll
      for (int i = 0; i < 4; i++)
        af[i] = *reinterpret_cast<const short8*>(&As[wm * 64 + i * 16 + l15][kk + klo]);
#pragma unroll
      for (int j = 0; j < 4; j++)
        bfb[j] = *reinterpret_cast<const short8*>(&Bs[wn * 64 + j * 16 + l15][kk + klo]);
#pragma unroll
      for (int i = 0; i < 4; i++)
#pragma unroll
        for (int j = 0; j < 4; j++)
          acc[i][j] = mfma16(af[i], bfb[j], acc[i][j]);
    }
    __syncthreads();
  }
  int lg4 = (lane >> 4) * 4;
#pragma unroll
  for (int i = 0; i < 4; i++) {
#pragma unroll
    for (int j = 0; j < 4; j++) {
      int n = bn * GBN + wn * 64 + j * 16 + l15;
      float bv = bias[n];
#pragma unroll
      for (int r = 0; r < 4; r++) {
        int m = bm * GBM + wm * 64 + i * 16 + lg4 + r;
        C[(size_t)m * Ndim + n] = f2bf(acc[i][j][r] + bv);
      }
    }
  }
}

// ---------------- recurrent layer: 16 WGs (8/dir), 512 thr, spin-synced -----
// WG (dir, slice): 64 units; wave w -> gate g=w>>1, unit half=w&1 (32 units).
// Whh hi/lo fragments register-resident. h packed (hi<<16|lo) in ypk.
__global__ __launch_bounds__(512, 1) void k_lstm2(const u16* __restrict__ xp,
                                                  const u16* __restrict__ whh_hi,
                                                  const u16* __restrict__ whh_lo,
                                                  u32* __restrict__ ypk,
                                                  u16* __restrict__ yh, int* cnt,
                                                  int write_yh) {
  int blk = blockIdx.x;
  int dir = blk & 1, slice = blk >> 1;  // slice 0..7
  int tid = threadIdx.x, wave = tid >> 6, lane = tid & 63;
  int g = wave >> 1, half = wave & 1;
  int u0 = slice * UPW;
  int l15 = lane & 15, lg = lane >> 4, klo = lg * 8;

  short8 wh[2][16], wl[2][16];
#pragma unroll
  for (int cg = 0; cg < 2; cg++) {
    size_t wr = ((size_t)dir * G4 + g * HID + u0 + half * 32 + cg * 16 + l15) * HID + klo;
#pragma unroll
    for (int kt = 0; kt < 16; kt++) {
      wh[cg][kt] = *reinterpret_cast<const short8*>(whh_hi + wr + kt * 32);
      wl[cg][kt] = *reinterpret_cast<const short8*>(whh_lo + wr + kt * 32);
    }
  }
  __shared__ float gx[4][NB][UPW];
  float cst[4] = {0.f, 0.f, 0.f, 0.f};
  int* mycnt = cnt + dir * T_SEQ;
  int xcol = dir * 2048 + g * HID + u0 + half * 32 + l15;

  for (int s = 0; s < T_SEQ; s++) {
    int trow = dir ? (T_SEQ - 1 - s) : s;
    f32x4 accM[2][2], accC[2][2];
    // xp prefetch into C-operand (issues before the spin)
#pragma unroll
    for (int mt = 0; mt < 2; mt++)
#pragma unroll
      for (int cg = 0; cg < 2; cg++) {
        const u16* xb = xp + (size_t)(trow * NB + mt * 16 + lg * 4) * XPW + xcol + cg * 16;
#pragma unroll
        for (int r = 0; r < 4; r++) accM[mt][cg][r] = bf2f(xb[(size_t)r * XPW]);
        accC[mt][cg] = (f32x4){0.f, 0.f, 0.f, 0.f};
      }
    if (s > 0 && tid == 0) {
      while (__hip_atomic_load(mycnt + s - 1, __ATOMIC_RELAXED,
                               __HIP_MEMORY_SCOPE_AGENT) < NWPD)
        __builtin_amdgcn_s_sleep(1);
      (void)__hip_atomic_load(mycnt + s - 1, __ATOMIC_ACQUIRE,
                              __HIP_MEMORY_SCOPE_AGENT);  // one inv per step
    }
    __syncthreads();
    if (s > 0) {
      int prow = dir ? (T_SEQ - s) : (s - 1);
      const u32* ybase = ypk + (size_t)(prow * NB) * 1024 + dir * HID;
#pragma unroll
      for (int kt = 0; kt < 16; kt++) {
        union { short8 s8; u32 u[4]; } ah[2], al[2];
#pragma unroll
        for (int mt = 0; mt < 2; mt++) {
          const uint4* p = reinterpret_cast<const uint4*>(
              ybase + (size_t)(mt * 16 + l15) * 1024 + kt * 32 + klo);
          uint4 a = p[0], b = p[1];
          u32 v[8] = {a.x, a.y, a.z, a.w, b.x, b.y, b.z, b.w};
#pragma unroll
          for (int i = 0; i < 4; i++) {
            ah[mt].u[i] = (v[2 * i + 1] & 0xFFFF0000u) | (v[2 * i] >> 16);
            al[mt].u[i] = (v[2 * i + 1] << 16) | (v[2 * i] & 0xFFFFu);
          }
        }
#pragma unroll
        for (int mt = 0; mt < 2; mt++)
#pragma unroll
          for (int cg = 0; cg < 2; cg++) {
            accM[mt][cg] = mfma16(ah[mt].s8, wh[cg][kt], accM[mt][cg]);
            accC[mt][cg] = mfma16(al[mt].s8, wh[cg][kt], accC[mt][cg]);
            accC[mt][cg] = mfma16(ah[mt].s8, wl[cg][kt], accC[mt][cg]);
          }
      }
    }
#pragma unroll
    for (int mt = 0; mt < 2; mt++)
#pragma unroll
      for (int cg = 0; cg < 2; cg++) {
        f32x4 v = accM[mt][cg] + accC[mt][cg];
#pragma unroll
        for (int r = 0; r < 4; r++)
          gx[g][mt * 16 + lg * 4 + r][half * 32 + cg * 16 + l15] = v[r];
      }
    __syncthreads();
#pragma unroll
    for (int j = 0; j < 4; j++) {
      int p = tid + 512 * j;
      int uu = p & 63, b = p >> 6;
      float gi = gx[0][b][uu], gf = gx[1][b][uu], gg = gx[2][b][uu], go = gx[3][b][uu];
      float iv = 1.f / (1.f + __expf(-gi));
      float fv = 1.f / (1.f + __expf(-gf));
      float gv = tanhf(gg);
      float ov = 1.f / (1.f + __expf(-go));
      float c = fv * cst[j] + iv * gv;
      cst[j] = c;
      float h = ov * tanhf(c);
      u16 hh = f2bf(h);
      u16 hl = f2bf(h - bf2f(hh));
      size_t yo = (size_t)(trow * NB + b) * 1024 + dir * HID + u0 + uu;
      __builtin_nontemporal_store(((u32)hh << 16) | hl, ypk + yo);
      if (write_yh) __builtin_nontemporal_store(hh, yh + yo);
    }
    __syncthreads();  // drains all waves' stores (vmcnt0 before barrier)
    if (tid == 0)
      __hip_atomic_fetch_add(mycnt + s, 1, __ATOMIC_RELEASE, __HIP_MEMORY_SCOPE_AGENT);
  }
}

// ---------------- final pooled dot ------------------------------------------
__global__ void k_out(const u32* __restrict__ ypk, const float* __restrict__ wout,
                      const float* __restrict__ bout, float* __restrict__ out) {
  int b = blockIdx.x;
  __shared__ float red[256];
  float s = 0.f;
  for (int c = threadIdx.x; c < 1024; c += 256) {
    size_t row = (c < 512) ? ((size_t)(T_SEQ - 1) * NB + b) : (size_t)b;
    u32 pk = ypk[row * 1024 + c];
    float h = bf2f((u16)(pk >> 16)) + bf2f((u16)(pk & 0xFFFFu));
    s += h * wout[c];
  }
  red[threadIdx.x] = s;
  __syncthreads();
  for (int st = 128; st > 0; st >>= 1) {
    if (threadIdx.x < st) red[threadIdx.x] += red[threadIdx.x + st];
    __syncthreads();
  }
  if (threadIdx.x == 0) out[b] = red[0] + bout[0];
}

extern "C" void kernel_launch(void* const* d_in, const int* in_sizes, int n_in,
                              void* d_out, int out_size, void* d_ws, size_t ws_size,
                              hipStream_t stream) {
  const int*   inp  = (const int*)d_in[0];
  const float* emb  = (const float*)d_in[1];
  const float* Wih  = (const float*)d_in[2];
  const float* Whh  = (const float*)d_in[3];
  const float* bih  = (const float*)d_in[4];
  const float* bhh  = (const float*)d_in[5];
  const float* Wout = (const float*)d_in[6];
  const float* bout = (const float*)d_in[7];
  float* out = (float*)d_out;
  char* ws = (char*)d_ws;

  const size_t SZ_XP  = (size_t)NROWS * XPW * 2;       // 134 MB bf16
  const size_t SZ_YPK = (size_t)NROWS * 1024 * 4;      // 67 MB packed u32
  const size_t SZ_YH  = (size_t)NROWS * 1024 * 2;      // 33.5 MB bf16
  const size_t SZ_WIH = (size_t)2 * 4096 * 1024 * 2;
  const size_t SZ_WHH = (size_t)2 * 2 * G4 * HID * 2;
  size_t off = 0;
  auto alloc = [&](size_t n) { size_t o = off; off += (n + 255) & ~(size_t)255; return o; };
  size_t o_xp   = alloc(SZ_XP);
  size_t o_ypk  = alloc(SZ_YPK);
  size_t o_y1h  = alloc(SZ_YH);
  size_t o_x1   = alloc(SZ_YH);
  size_t o_wih  = alloc(SZ_WIH);
  size_t o_whhh = alloc(SZ_WHH);
  size_t o_whhl = alloc(SZ_WHH);
  size_t o_bc   = alloc(2 * 4096 * sizeof(float));
  size_t o_cnt  = alloc(2 * 2 * T_SEQ * sizeof(int));
  if (ws_size < off) return;

  u16* xp   = (u16*)(ws + o_xp);
  u32* ypk  = (u32*)(ws + o_ypk);
  u16* y1h  = (u16*)(ws + o_y1h);
  u16* x1   = (u16*)(ws + o_x1);
  u16* wihb = (u16*)(ws + o_wih);
  u16* whhh = (u16*)(ws + o_whhh);
  u16* whhl = (u16*)(ws + o_whhl);
  float* bc = (float*)(ws + o_bc);
  int* cnt  = (int*)(ws + o_cnt);

  hipMemsetAsync(cnt, 0, 2 * 2 * T_SEQ * sizeof(int), stream);
  k_prep<<<4096, 256, 0, stream>>>(Wih, Whh, bih, bhh, wihb, whhh, whhl, bc);
  k_gather<<<NROWS, 256, 0, stream>>>(inp, emb, x1);
  k_gemm<<<dim3(NROWS / GBM, XPW / GBN), 256, 0, stream>>>(x1, wihb, bc, xp);
  k_lstm2<<<2 * NWPD, 512, 0, stream>>>(xp, whhh, whhl, ypk, y1h, cnt, 1);
  k_gemm<<<dim3(NROWS / GBM, XPW / GBN), 256, 0, stream>>>(
      y1h, wihb + (size_t)4096 * 1024, bc + 4096, xp);
  k_lstm2<<<2 * NWPD, 512, 0, stream>>>(xp, whhh + (size_t)2 * G4 * HID,
                                        whhl + (size_t)2 * G4 * HID, ypk, y1h,
                                        cnt + 2 * T_SEQ, 0);
  k_out<<<NB, 256, 0, stream>>>(ypk, Wout, bout, out);
}

// Round 3
// 14102.924 us; speedup vs baseline: 1.9734x; 1.9734x over previous
//
#include <hip/hip_runtime.h>
#include <stdint.h>

typedef unsigned short u16;
typedef __attribute__((ext_vector_type(8))) short short8;
typedef __attribute__((ext_vector_type(4))) float f32x4;

#define T_SEQ 512
#define NB 32
#define EMBD 1024
#define HID 512
#define G4 2048
#define NROWS (T_SEQ * NB)  // 16384
#define XPW 4096
#define WPD 32  // workgroups per direction

static __device__ __forceinline__ u16 f2bf(float x) {
  unsigned u = __float_as_uint(x);
  u += 0x7fffu + ((u >> 16) & 1u);
  return (u16)(u >> 16);
}
static __device__ __forceinline__ float bf2f(u16 b) {
  return __uint_as_float(((unsigned)b) << 16);
}
static __device__ __forceinline__ f32x4 mfma16(short8 a, short8 b, f32x4 c) {
  return __builtin_amdgcn_mfma_f32_16x16x32_bf16(a, b, c, 0, 0, 0);
}

// ---------------- weight prep: bf16 convert, Whh split hi/lo, bias merge ----
__global__ void k_prep(const float* __restrict__ Wih, const float* __restrict__ Whh,
                       const float* __restrict__ bih, const float* __restrict__ bhh,
                       u16* __restrict__ wih_b, u16* __restrict__ whh_hi,
                       u16* __restrict__ whh_lo, float* __restrict__ bcat) {
  size_t stride = (size_t)gridDim.x * blockDim.x;
  size_t i0 = (size_t)blockIdx.x * blockDim.x + threadIdx.x;
  const size_t n_ih = (size_t)2 * 2 * G4 * EMBD;  // [l][d][4H][E]
  for (size_t i = i0; i < n_ih; i += stride) wih_b[i] = f2bf(Wih[i]);
  const size_t n_hh = (size_t)2 * 2 * G4 * HID;   // [l][d][4H][H]
  for (size_t i = i0; i < n_hh; i += stride) {
    float w = Whh[i];
    u16 hi = f2bf(w);
    whh_hi[i] = hi;
    whh_lo[i] = f2bf(w - bf2f(hi));
  }
  for (size_t i = i0; i < 2 * 4096; i += stride) {
    size_t l = i >> 12, col = i & 4095;  // col = d*2048+g*512+u
    bcat[i] = bih[l * 4096 + col] + bhh[l * 4096 + col];
  }
}

// ---------------- embedding gather -> bf16 X [T*B, 1024] --------------------
__global__ void k_gather(const int* __restrict__ inp, const float* __restrict__ emb,
                         u16* __restrict__ X) {
  int row = blockIdx.x;  // t*32 + b
  int t = row >> 5, b = row & 31;
  int tok = inp[b * T_SEQ + t];
  const float* src = emb + (size_t)tok * EMBD + threadIdx.x * 4;
  float4 v = *reinterpret_cast<const float4*>(src);
  ushort4 o;
  o.x = f2bf(v.x); o.y = f2bf(v.y); o.z = f2bf(v.z); o.w = f2bf(v.w);
  *reinterpret_cast<ushort4*>(X + (size_t)row * EMBD + threadIdx.x * 4) = o;
}

// ---------------- xp GEMM: C[M,4096] = A[M,1024] @ B[4096,1024]^T + bias ----
#define GBM 128
#define GBN 128
#define GBK 64
__global__ __launch_bounds__(256) void k_gemm(const u16* __restrict__ A,
                                              const u16* __restrict__ B,
                                              const float* __restrict__ bias,
                                              u16* __restrict__ C) {
  __shared__ u16 As[GBM][GBK];
  __shared__ u16 Bs[GBN][GBK];
  const int Kdim = 1024, Ndim = 4096;
  int bm = blockIdx.x, bn = blockIdx.y;
  int tid = threadIdx.x;
  int lane = tid & 63, wave = tid >> 6;
  int wm = wave >> 1, wn = wave & 1;
  int l15 = lane & 15, klo = (lane >> 4) * 8;
  f32x4 acc[4][4] = {};
  for (int k0 = 0; k0 < Kdim; k0 += GBK) {
#pragma unroll
    for (int s = 0; s < 4; s++) {
      int seg = tid + s * 256;
      int r = seg >> 3, cs = (seg & 7) * 8;
      *reinterpret_cast<short8*>(&As[r][cs]) =
          *reinterpret_cast<const short8*>(A + (size_t)(bm * GBM + r) * Kdim + k0 + cs);
      *reinterpret_cast<short8*>(&Bs[r][cs]) =
          *reinterpret_cast<const short8*>(B + (size_t)(bn * GBN + r) * Kdim + k0 + cs);
    }
    __syncthreads();
#pragma unroll
    for (int kk = 0; kk < GBK; kk += 32) {
      short8 af[4], bfb[4];
#pragma unroll
      for (int i = 0; i < 4; i++)
        af[i] = *reinterpret_cast<const short8*>(&As[wm * 64 + i * 16 + l15][kk + klo]);
#pragma unroll
      for (int j = 0; j < 4; j++)
        bfb[j] = *reinterpret_cast<const short8*>(&Bs[wn * 64 + j * 16 + l15][kk + klo]);
#pragma unroll
      for (int i = 0; i < 4; i++)
#pragma unroll
        for (int j = 0; j < 4; j++)
          acc[i][j] = mfma16(af[i], bfb[j], acc[i][j]);
    }
    __syncthreads();
  }
  int lg4 = (lane >> 4) * 4;
#pragma unroll
  for (int i = 0; i < 4; i++) {
#pragma unroll
    for (int j = 0; j < 4; j++) {
      int n = bn * GBN + wn * 64 + j * 16 + l15;
      float bv = bias[n];
#pragma unroll
      for (int r = 0; r < 4; r++) {
        int m = bm * GBM + wm * 64 + i * 16 + lg4 + r;
        C[(size_t)m * Ndim + n] = f2bf(acc[i][j][r] + bv);
      }
    }
  }
}

// ---------------- recurrent layer: 64 WGs (32/dir), spin-synced -------------
// WG (dir, slice): 16 hidden units; wave w = gate w. Weights register-resident.
// Sync: per-WG flag slots (release store), wave-parallel relaxed spin,
// ONE acquire inv per step, nontemporal h stores, no threadfence.
__global__ __launch_bounds__(256, 1) void k_lstm3(const u16* __restrict__ xp,
                                                  const u16* __restrict__ whh_hi,
                                                  const u16* __restrict__ whh_lo,
                                                  u16* __restrict__ Yhi,
                                                  u16* __restrict__ Ylo,
                                                  int* __restrict__ flags) {
  int blk = blockIdx.x;
  int dir = blk >> 5, slice = blk & 31;
  int tid = threadIdx.x, wave = tid >> 6, lane = tid & 63;
  int u0 = slice * 16;
  int l15 = lane & 15, lg = lane >> 4;
  int klo = lg * 8;
  short8 wh[16], wl[16];
  {
    size_t wroff = ((size_t)dir * G4 + wave * HID + u0 + l15) * HID + klo;
#pragma unroll
    for (int kt = 0; kt < 16; kt++) {
      wh[kt] = *reinterpret_cast<const short8*>(whh_hi + wroff + kt * 32);
      wl[kt] = *reinterpret_cast<const short8*>(whh_lo + wroff + kt * 32);
    }
  }
  __shared__ float gx[4][32][16];  // [gate][b][uu]
  float c0 = 0.f, c1 = 0.f;
  int* myflags = flags + dir * T_SEQ * WPD;  // [s][wg]
  int xcol = dir * 2048 + wave * HID + u0 + l15;
  for (int s = 0; s < T_SEQ; s++) {
    int trow = dir ? (T_SEQ - 1 - s) : s;
    f32x4 z = {0.f, 0.f, 0.f, 0.f};
    f32x4 acc0 = z, acc1 = z, acc2 = z, acc3 = z, acc4 = z, acc5 = z;
    {  // prefetch xp slice into acc (issues before the spin)
      const u16* xb = xp + (size_t)trow * NB * XPW + xcol;
#pragma unroll
      for (int r = 0; r < 4; r++) {
        acc0[r] = bf2f(xb[(size_t)(4 * lg + r) * XPW]);
        acc1[r] = bf2f(xb[(size_t)(16 + 4 * lg + r) * XPW]);
      }
    }
    if (s > 0) {
      if (wave == 0) {  // 64 lanes poll the 32 slots (1 cache line)
        int* slot = myflags + (s - 1) * WPD + (lane & 31);
        int v;
        do {
          v = __hip_atomic_load(slot, __ATOMIC_RELAXED, __HIP_MEMORY_SCOPE_AGENT);
          if (__all(v != 0)) break;
          __builtin_amdgcn_s_sleep(1);
        } while (1);
        if (lane == 0)  // single acquire -> one buffer_inv per step
          (void)__hip_atomic_load(myflags + (s - 1) * WPD, __ATOMIC_ACQUIRE,
                                  __HIP_MEMORY_SCOPE_AGENT);
      }
      __syncthreads();
      int prow = dir ? (T_SEQ - s) : (s - 1);
      const u16* yb  = Yhi + ((size_t)prow * NB + l15) * 1024 + dir * HID + klo;
      const u16* ybl = Ylo + ((size_t)prow * NB + l15) * 1024 + dir * HID + klo;
#pragma unroll
      for (int kt = 0; kt < 16; kt++) {
        short8 ah0 = *reinterpret_cast<const short8*>(yb + kt * 32);
        short8 ah1 = *reinterpret_cast<const short8*>(yb + 16 * 1024 + kt * 32);
        short8 al0 = *reinterpret_cast<const short8*>(ybl + kt * 32);
        short8 al1 = *reinterpret_cast<const short8*>(ybl + 16 * 1024 + kt * 32);
        acc0 = mfma16(ah0, wh[kt], acc0);
        acc1 = mfma16(ah1, wh[kt], acc1);
        acc2 = mfma16(al0, wh[kt], acc2);
        acc3 = mfma16(al1, wh[kt], acc3);
        acc4 = mfma16(ah0, wl[kt], acc4);
        acc5 = mfma16(ah1, wl[kt], acc5);
      }
      acc0 += acc2; acc0 += acc4;
      acc1 += acc3; acc1 += acc5;
    }
#pragma unroll
    for (int r = 0; r < 4; r++) {
      gx[wave][4 * lg + r][l15] = acc0[r];
      gx[wave][16 + 4 * lg + r][l15] = acc1[r];
    }
    __syncthreads();
#pragma unroll
    for (int j = 0; j < 2; j++) {
      int p = tid + 256 * j;
      int uu = p & 15, b = p >> 4;
      float gi = gx[0][b][uu], gf = gx[1][b][uu], gg = gx[2][b][uu], go = gx[3][b][uu];
      float iv = 1.f / (1.f + __expf(-gi));
      float fv = 1.f / (1.f + __expf(-gf));
      float gv = tanhf(gg);
      float ov = 1.f / (1.f + __expf(-go));
      float& c = j ? c1 : c0;
      c = fv * c + iv * gv;
      float h = ov * tanhf(c);
      u16 hh = f2bf(h);
      u16 hl = f2bf(h - bf2f(hh));
      size_t yo = ((size_t)trow * NB + b) * 1024 + dir * HID + u0 + uu;
      __builtin_nontemporal_store(hh, Yhi + yo);  // L2 stays clean
      __builtin_nontemporal_store(hl, Ylo + yo);
    }
    __syncthreads();  // all waves' stores drained (vmcnt0 before barrier)
    if (tid == 0)
      __hip_atomic_store(myflags + s * WPD + slice, 1, __ATOMIC_RELEASE,
                         __HIP_MEMORY_SCOPE_AGENT);
  }
}

// ---------------- final pooled dot ------------------------------------------
__global__ void k_out(const u16* __restrict__ Yhi, const u16* __restrict__ Ylo,
                      const float* __restrict__ wout, const float* __restrict__ bout,
                      float* __restrict__ out) {
  int b = blockIdx.x;
  __shared__ float red[256];
  float s = 0.f;
  for (int c = threadIdx.x; c < 1024; c += 256) {
    size_t row = (c < 512) ? ((size_t)(T_SEQ - 1) * NB + b) : (size_t)b;
    float h = bf2f(Yhi[row * 1024 + c]) + bf2f(Ylo[row * 1024 + c]);
    s += h * wout[c];
  }
  red[threadIdx.x] = s;
  __syncthreads();
  for (int st = 128; st > 0; st >>= 1) {
    if (threadIdx.x < st) red[threadIdx.x] += red[threadIdx.x + st];
    __syncthreads();
  }
  if (threadIdx.x == 0) out[b] = red[0] + bout[0];
}

extern "C" void kernel_launch(void* const* d_in, const int* in_sizes, int n_in,
                              void* d_out, int out_size, void* d_ws, size_t ws_size,
                              hipStream_t stream) {
  const int*   inp  = (const int*)d_in[0];
  const float* emb  = (const float*)d_in[1];
  const float* Wih  = (const float*)d_in[2];
  const float* Whh  = (const float*)d_in[3];
  const float* bih  = (const float*)d_in[4];
  const float* bhh  = (const float*)d_in[5];
  const float* Wout = (const float*)d_in[6];
  const float* bout = (const float*)d_in[7];
  float* out = (float*)d_out;
  char* ws = (char*)d_ws;

  const size_t SZ_XP  = (size_t)NROWS * XPW * 2;
  const size_t SZ_Y   = (size_t)NROWS * 1024 * 2;
  const size_t SZ_WIH = (size_t)2 * 4096 * 1024 * 2;
  const size_t SZ_WHH = (size_t)2 * 2 * G4 * HID * 2;
  const size_t SZ_FLG = (size_t)2 * 2 * T_SEQ * WPD * sizeof(int);  // 256KB
  size_t off = 0;
  auto alloc = [&](size_t n) { size_t o = off; off += (n + 255) & ~(size_t)255; return o; };
  size_t o_xp   = alloc(SZ_XP);
  size_t o_y1h  = alloc(SZ_Y);
  size_t o_y1l  = alloc(SZ_Y);
  size_t o_y2h  = alloc(SZ_Y);   // aliased as X1 (embedding) before layer 2
  size_t o_y2l  = alloc(SZ_Y);
  size_t o_wih  = alloc(SZ_WIH);
  size_t o_whhh = alloc(SZ_WHH);
  size_t o_whhl = alloc(SZ_WHH);
  size_t o_bc   = alloc(2 * 4096 * sizeof(float));
  size_t o_flg  = alloc(SZ_FLG);
  if (ws_size < off) return;

  u16* xp   = (u16*)(ws + o_xp);
  u16* y1h  = (u16*)(ws + o_y1h);
  u16* y1l  = (u16*)(ws + o_y1l);
  u16* y2h  = (u16*)(ws + o_y2h);
  u16* y2l  = (u16*)(ws + o_y2l);
  u16* x1   = y2h;  // alias: dead before k_lstm3 layer-2 writes y2h
  u16* wihb = (u16*)(ws + o_wih);
  u16* whhh = (u16*)(ws + o_whhh);
  u16* whhl = (u16*)(ws + o_whhl);
  float* bc = (float*)(ws + o_bc);
  int* flg  = (int*)(ws + o_flg);

  hipMemsetAsync(flg, 0, SZ_FLG, stream);
  k_prep<<<4096, 256, 0, stream>>>(Wih, Whh, bih, bhh, wihb, whhh, whhl, bc);
  k_gather<<<NROWS, 256, 0, stream>>>(inp, emb, x1);
  k_gemm<<<dim3(NROWS / GBM, XPW / GBN), 256, 0, stream>>>(x1, wihb, bc, xp);
  k_lstm3<<<2 * WPD, 256, 0, stream>>>(xp, whhh, whhl, y1h, y1l, flg);
  k_gemm<<<dim3(NROWS / GBM, XPW / GBN), 256, 0, stream>>>(
      y1h, wihb + (size_t)4096 * 1024, bc + 4096, xp);
  k_lstm3<<<2 * WPD, 256, 0, stream>>>(xp, whhh + (size_t)2 * G4 * HID,
                                       whhl + (size_t)2 * G4 * HID, y2h, y2l,
                                       flg + 2 * T_SEQ * WPD);
  k_out<<<NB, 256, 0, stream>>>(y2h, y2l, Wout, bout, out);
}

// Round 4
// 7957.960 us; speedup vs baseline: 3.4971x; 1.7722x over previous
//
#include <hip/hip_runtime.h>
#include <stdint.h>

typedef unsigned short u16;
typedef __attribute__((ext_vector_type(8))) short short8;
typedef __attribute__((ext_vector_type(4))) float f32x4;

#define T_SEQ 512
#define NB 32
#define EMBD 1024
#define HID 512
#define G4 2048
#define NROWS (T_SEQ * NB)  // 16384
#define XPW 4096
#define WPD 32  // workgroups per direction

static __device__ __forceinline__ u16 f2bf(float x) {
  unsigned u = __float_as_uint(x);
  u += 0x7fffu + ((u >> 16) & 1u);
  return (u16)(u >> 16);
}
static __device__ __forceinline__ float bf2f(u16 b) {
  return __uint_as_float(((unsigned)b) << 16);
}
static __device__ __forceinline__ f32x4 mfma16(short8 a, short8 b, f32x4 c) {
  return __builtin_amdgcn_mfma_f32_16x16x32_bf16(a, b, c, 0, 0, 0);
}

// ---------------- weight prep: bf16 convert, Whh split hi/lo, bias merge ----
__global__ void k_prep(const float* __restrict__ Wih, const float* __restrict__ Whh,
                       const float* __restrict__ bih, const float* __restrict__ bhh,
                       u16* __restrict__ wih_b, u16* __restrict__ whh_hi,
                       u16* __restrict__ whh_lo, float* __restrict__ bcat) {
  size_t stride = (size_t)gridDim.x * blockDim.x;
  size_t i0 = (size_t)blockIdx.x * blockDim.x + threadIdx.x;
  const size_t n_ih = (size_t)2 * 2 * G4 * EMBD;  // [l][d][4H][E]
  for (size_t i = i0; i < n_ih; i += stride) wih_b[i] = f2bf(Wih[i]);
  const size_t n_hh = (size_t)2 * 2 * G4 * HID;   // [l][d][4H][H]
  for (size_t i = i0; i < n_hh; i += stride) {
    float w = Whh[i];
    u16 hi = f2bf(w);
    whh_hi[i] = hi;
    whh_lo[i] = f2bf(w - bf2f(hi));
  }
  for (size_t i = i0; i < 2 * 4096; i += stride) {
    size_t l = i >> 12, col = i & 4095;  // col = d*2048+g*512+u
    bcat[i] = bih[l * 4096 + col] + bhh[l * 4096 + col];
  }
}

// ---------------- embedding gather -> bf16 X [T*B, 1024] --------------------
__global__ void k_gather(const int* __restrict__ inp, const float* __restrict__ emb,
                         u16* __restrict__ X) {
  int row = blockIdx.x;  // t*32 + b
  int t = row >> 5, b = row & 31;
  int tok = inp[b * T_SEQ + t];
  const float* src = emb + (size_t)tok * EMBD + threadIdx.x * 4;
  float4 v = *reinterpret_cast<const float4*>(src);
  ushort4 o;
  o.x = f2bf(v.x); o.y = f2bf(v.y); o.z = f2bf(v.z); o.w = f2bf(v.w);
  *reinterpret_cast<ushort4*>(X + (size_t)row * EMBD + threadIdx.x * 4) = o;
}

// ---------------- xp GEMM: C[M,4096] = A[M,1024] @ B[4096,1024]^T + bias ----
#define GBM 128
#define GBN 128
#define GBK 64
__global__ __launch_bounds__(256) void k_gemm(const u16* __restrict__ A,
                                              const u16* __restrict__ B,
                                              const float* __restrict__ bias,
                                              u16* __restrict__ C) {
  __shared__ u16 As[GBM][GBK];
  __shared__ u16 Bs[GBN][GBK];
  const int Kdim = 1024, Ndim = 4096;
  int bm = blockIdx.x, bn = blockIdx.y;
  int tid = threadIdx.x;
  int lane = tid & 63, wave = tid >> 6;
  int wm = wave >> 1, wn = wave & 1;
  int l15 = lane & 15, klo = (lane >> 4) * 8;
  f32x4 acc[4][4] = {};
  for (int k0 = 0; k0 < Kdim; k0 += GBK) {
#pragma unroll
    for (int s = 0; s < 4; s++) {
      int seg = tid + s * 256;
      int r = seg >> 3, cs = (seg & 7) * 8;
      *reinterpret_cast<short8*>(&As[r][cs]) =
          *reinterpret_cast<const short8*>(A + (size_t)(bm * GBM + r) * Kdim + k0 + cs);
      *reinterpret_cast<short8*>(&Bs[r][cs]) =
          *reinterpret_cast<const short8*>(B + (size_t)(bn * GBN + r) * Kdim + k0 + cs);
    }
    __syncthreads();
#pragma unroll
    for (int kk = 0; kk < GBK; kk += 32) {
      short8 af[4], bfb[4];
#pragma unroll
      for (int i = 0; i < 4; i++)
        af[i] = *reinterpret_cast<const short8*>(&As[wm * 64 + i * 16 + l15][kk + klo]);
#pragma unroll
      for (int j = 0; j < 4; j++)
        bfb[j] = *reinterpret_cast<const short8*>(&Bs[wn * 64 + j * 16 + l15][kk + klo]);
#pragma unroll
      for (int i = 0; i < 4; i++)
#pragma unroll
        for (int j = 0; j < 4; j++)
          acc[i][j] = mfma16(af[i], bfb[j], acc[i][j]);
    }
    __syncthreads();
  }
  int lg4 = (lane >> 4) * 4;
#pragma unroll
  for (int i = 0; i < 4; i++) {
#pragma unroll
    for (int j = 0; j < 4; j++) {
      int n = bn * GBN + wn * 64 + j * 16 + l15;
      float bv = bias[n];
#pragma unroll
      for (int r = 0; r < 4; r++) {
        int m = bm * GBM + wm * 64 + i * 16 + lg4 + r;
        C[(size_t)m * Ndim + n] = f2bf(acc[i][j][r] + bv);
      }
    }
  }
}

// ---------------- recurrent layer: 64 WGs (32/dir), K-split waves -----------
// WG (dir, slice): 16 hidden units, all 4 gates. Wave w = K-slice
// [w*128,(w+1)*128): computes partial gate sums for all 4 gates, reduced via
// LDS. Weights (hi+lo) pinned in VGPRs via asm. Per-wave h read = 16 KB.
__global__ __launch_bounds__(256, 1) void k_lstm4(const u16* __restrict__ xp,
                                                  const u16* __restrict__ whh_hi,
                                                  const u16* __restrict__ whh_lo,
                                                  u16* __restrict__ Yhi,
                                                  u16* __restrict__ Ylo,
                                                  int* __restrict__ flags) {
  int blk = blockIdx.x;
  int dir = blk >> 5, slice = blk & 31;
  int tid = threadIdx.x, wave = tid >> 6, lane = tid & 63;
  int u0 = slice * 16;
  int l15 = lane & 15, lg = lane >> 4;
  int klo = lg * 8;

  // Weight fragments: [gate ct][kt], K-cols wave*128 + kt*32 + klo .. +7
  f32x4 whf[4][4], wlf[4][4];
#pragma unroll
  for (int ct = 0; ct < 4; ct++) {
    size_t wr = ((size_t)dir * G4 + ct * HID + u0 + l15) * HID + wave * 128 + klo;
#pragma unroll
    for (int kt = 0; kt < 4; kt++) {
      whf[ct][kt] = *reinterpret_cast<const f32x4*>(whh_hi + wr + kt * 32);
      wlf[ct][kt] = *reinterpret_cast<const f32x4*>(whh_lo + wr + kt * 32);
    }
  }
  // Pin in registers: loads cannot sink into the step loop.
#pragma unroll
  for (int ct = 0; ct < 4; ct++)
#pragma unroll
    for (int kt = 0; kt < 4; kt++) {
      asm volatile("" : "+v"(whf[ct][kt]));
      asm volatile("" : "+v"(wlf[ct][kt]));
    }

  __shared__ float pgx[4][NB][16][4];  // [gate][b][uu][wave] partials, 32 KB
  float cst[2] = {0.f, 0.f};
  int* myflags = flags + dir * T_SEQ * WPD;  // [s][wg]
  // reducer-thread coordinates (j = 0,1)
  int bj[2], uj[2];
#pragma unroll
  for (int j = 0; j < 2; j++) {
    int p = tid + 256 * j;
    uj[j] = p & 15;
    bj[j] = p >> 4;
  }

  for (int s = 0; s < T_SEQ; s++) {
    int trow = dir ? (T_SEQ - 1 - s) : s;
    // xp prefetch for the reducer phase (issues before the spin)
    float xq[2][4];
#pragma unroll
    for (int j = 0; j < 2; j++) {
      const u16* xb = xp + (size_t)(trow * NB + bj[j]) * XPW + dir * 2048 + u0 + uj[j];
#pragma unroll
      for (int g = 0; g < 4; g++) xq[j][g] = bf2f(xb[g * HID]);
    }
    if (s > 0) {
      if (wave == 0) {  // 64 lanes poll the 32 slots (1 cache line)
        int* slot = myflags + (s - 1) * WPD + (lane & 31);
        int v;
        do {
          v = __hip_atomic_load(slot, __ATOMIC_RELAXED, __HIP_MEMORY_SCOPE_AGENT);
          if (__all(v != 0)) break;
          __builtin_amdgcn_s_sleep(1);
        } while (1);
        if (lane == 0)  // single acquire -> one inv per step
          (void)__hip_atomic_load(myflags + (s - 1) * WPD, __ATOMIC_ACQUIRE,
                                  __HIP_MEMORY_SCOPE_AGENT);
      }
    }
    __syncthreads();
    if (s > 0) {
      int prow = dir ? (T_SEQ - s) : (s - 1);
      // h fragments: rows mt*16+l15, K-cols wave*128 + kt*32 + klo
      const u16* yb  = Yhi + ((size_t)prow * NB + l15) * 1024 + dir * HID + wave * 128 + klo;
      const u16* ybl = Ylo + ((size_t)prow * NB + l15) * 1024 + dir * HID + wave * 128 + klo;
      short8 ah[2][4], al[2][4];
#pragma unroll
      for (int mt = 0; mt < 2; mt++)
#pragma unroll
        for (int kt = 0; kt < 4; kt++) {
          ah[mt][kt] = *reinterpret_cast<const short8*>(yb + mt * 16 * 1024 + kt * 32);
          al[mt][kt] = *reinterpret_cast<const short8*>(ybl + mt * 16 * 1024 + kt * 32);
        }
      f32x4 accM[2][4], accC[2][4];
#pragma unroll
      for (int mt = 0; mt < 2; mt++)
#pragma unroll
        for (int ct = 0; ct < 4; ct++) {
          accM[mt][ct] = (f32x4){0.f, 0.f, 0.f, 0.f};
          accC[mt][ct] = (f32x4){0.f, 0.f, 0.f, 0.f};
        }
#pragma unroll
      for (int kt = 0; kt < 4; kt++)
#pragma unroll
        for (int mt = 0; mt < 2; mt++)
#pragma unroll
          for (int ct = 0; ct < 4; ct++) {
            short8 wh = __builtin_bit_cast(short8, whf[ct][kt]);
            short8 wl = __builtin_bit_cast(short8, wlf[ct][kt]);
            accM[mt][ct] = mfma16(ah[mt][kt], wh, accM[mt][ct]);
            accC[mt][ct] = mfma16(al[mt][kt], wh, accC[mt][ct]);
            accC[mt][ct] = mfma16(ah[mt][kt], wl, accC[mt][ct]);
          }
      // write partials: batch b = mt*16 + lg*4 + r, unit l15, gate ct, slice wave
#pragma unroll
      for (int mt = 0; mt < 2; mt++)
#pragma unroll
        for (int ct = 0; ct < 4; ct++) {
          f32x4 v = accM[mt][ct] + accC[mt][ct];
#pragma unroll
          for (int r = 0; r < 4; r++)
            pgx[ct][mt * 16 + lg * 4 + r][l15][wave] = v[r];
        }
    }
    __syncthreads();
    // reduce partials + elementwise + h store
#pragma unroll
    for (int j = 0; j < 2; j++) {
      int b = bj[j], uu = uj[j];
      float gs[4];
#pragma unroll
      for (int g = 0; g < 4; g++) {
        float v = xq[j][g];
        if (s > 0) {
          float4 q = *reinterpret_cast<const float4*>(&pgx[g][b][uu][0]);
          v += (q.x + q.y) + (q.z + q.w);
        }
        gs[g] = v;
      }
      float iv = 1.f / (1.f + __expf(-gs[0]));
      float fv = 1.f / (1.f + __expf(-gs[1]));
      float gv = tanhf(gs[2]);
      float ov = 1.f / (1.f + __expf(-gs[3]));
      float c = fv * cst[j] + iv * gv;
      cst[j] = c;
      float h = ov * tanhf(c);
      u16 hh = f2bf(h);
      u16 hl = f2bf(h - bf2f(hh));
      size_t yo = ((size_t)trow * NB + b) * 1024 + dir * HID + u0 + uu;
      __builtin_nontemporal_store(hh, Yhi + yo);  // L2 stays clean
      __builtin_nontemporal_store(hl, Ylo + yo);
    }
    __syncthreads();  // all threads' stores drained (vmcnt0 before barrier)
    if (tid == 0)
      __hip_atomic_store(myflags + s * WPD + slice, 1, __ATOMIC_RELEASE,
                         __HIP_MEMORY_SCOPE_AGENT);
  }
}

// ---------------- final pooled dot ------------------------------------------
__global__ void k_out(const u16* __restrict__ Yhi, const u16* __restrict__ Ylo,
                      const float* __restrict__ wout, const float* __restrict__ bout,
                      float* __restrict__ out) {
  int b = blockIdx.x;
  __shared__ float red[256];
  float s = 0.f;
  for (int c = threadIdx.x; c < 1024; c += 256) {
    size_t row = (c < 512) ? ((size_t)(T_SEQ - 1) * NB + b) : (size_t)b;
    float h = bf2f(Yhi[row * 1024 + c]) + bf2f(Ylo[row * 1024 + c]);
    s += h * wout[c];
  }
  red[threadIdx.x] = s;
  __syncthreads();
  for (int st = 128; st > 0; st >>= 1) {
    if (threadIdx.x < st) red[threadIdx.x] += red[threadIdx.x + st];
    __syncthreads();
  }
  if (threadIdx.x == 0) out[b] = red[0] + bout[0];
}

extern "C" void kernel_launch(void* const* d_in, const int* in_sizes, int n_in,
                              void* d_out, int out_size, void* d_ws, size_t ws_size,
                              hipStream_t stream) {
  const int*   inp  = (const int*)d_in[0];
  const float* emb  = (const float*)d_in[1];
  const float* Wih  = (const float*)d_in[2];
  const float* Whh  = (const float*)d_in[3];
  const float* bih  = (const float*)d_in[4];
  const float* bhh  = (const float*)d_in[5];
  const float* Wout = (const float*)d_in[6];
  const float* bout = (const float*)d_in[7];
  float* out = (float*)d_out;
  char* ws = (char*)d_ws;

  const size_t SZ_XP  = (size_t)NROWS * XPW * 2;
  const size_t SZ_Y   = (size_t)NROWS * 1024 * 2;
  const size_t SZ_WIH = (size_t)2 * 4096 * 1024 * 2;
  const size_t SZ_WHH = (size_t)2 * 2 * G4 * HID * 2;
  const size_t SZ_FLG = (size_t)2 * 2 * T_SEQ * WPD * sizeof(int);  // 256KB
  size_t off = 0;
  auto alloc = [&](size_t n) { size_t o = off; off += (n + 255) & ~(size_t)255; return o; };
  size_t o_xp   = alloc(SZ_XP);
  size_t o_y1h  = alloc(SZ_Y);
  size_t o_y1l  = alloc(SZ_Y);
  size_t o_y2h  = alloc(SZ_Y);   // aliased as X1 (embedding) before layer 2
  size_t o_y2l  = alloc(SZ_Y);
  size_t o_wih  = alloc(SZ_WIH);
  size_t o_whhh = alloc(SZ_WHH);
  size_t o_whhl = alloc(SZ_WHH);
  size_t o_bc   = alloc(2 * 4096 * sizeof(float));
  size_t o_flg  = alloc(SZ_FLG);
  if (ws_size < off) return;

  u16* xp   = (u16*)(ws + o_xp);
  u16* y1h  = (u16*)(ws + o_y1h);
  u16* y1l  = (u16*)(ws + o_y1l);
  u16* y2h  = (u16*)(ws + o_y2h);
  u16* y2l  = (u16*)(ws + o_y2l);
  u16* x1   = y2h;  // alias: dead before k_lstm4 layer-2 writes y2h
  u16* wihb = (u16*)(ws + o_wih);
  u16* whhh = (u16*)(ws + o_whhh);
  u16* whhl = (u16*)(ws + o_whhl);
  float* bc = (float*)(ws + o_bc);
  int* flg  = (int*)(ws + o_flg);

  hipMemsetAsync(flg, 0, SZ_FLG, stream);
  k_prep<<<4096, 256, 0, stream>>>(Wih, Whh, bih, bhh, wihb, whhh, whhl, bc);
  k_gather<<<NROWS, 256, 0, stream>>>(inp, emb, x1);
  k_gemm<<<dim3(NROWS / GBM, XPW / GBN), 256, 0, stream>>>(x1, wihb, bc, xp);
  k_lstm4<<<2 * WPD, 256, 0, stream>>>(xp, whhh, whhl, y1h, y1l, flg);
  k_gemm<<<dim3(NROWS / GBM, XPW / GBN), 256, 0, stream>>>(
      y1h, wihb + (size_t)4096 * 1024, bc + 4096, xp);
  k_lstm4<<<2 * WPD, 256, 0, stream>>>(xp, whhh + (size_t)2 * G4 * HID,
                                       whhl + (size_t)2 * G4 * HID, y2h, y2l,
                                       flg + 2 * T_SEQ * WPD);
  k_out<<<NB, 256, 0, stream>>>(y2h, y2l, Wout, bout, out);
}